// Round 1
// baseline (910.613 us; speedup 1.0000x reference)
//
#include <hip/hip_runtime.h>
#include <stdint.h>

#define T_FRAMES 32
#define NNODES 10000
#define NEDGES 160000
#define HID 128

static __device__ __forceinline__ ushort f2bf(float f){
  uint32_t u = __float_as_uint(f);
  u += 0x7FFFu + ((u >> 16) & 1u);
  return (ushort)(u >> 16);
}
static __device__ __forceinline__ float bf2f(ushort h){
  return __uint_as_float(((uint32_t)h) << 16);
}
static __device__ __forceinline__ float silu_f(float x){
  return x / (1.0f + expf(-x));
}
static __device__ __forceinline__ float sigm_f(float x){
  return 1.0f / (1.0f + expf(-x));
}

// ---------------- degree / norms / CSR build ----------------

__global__ void k_degree(const int* __restrict__ src, const int* __restrict__ dst,
                         int* cnt_out, int* cnt_in, int E){
  int e = blockIdx.x*blockDim.x + threadIdx.x;
  if (e < E){
    atomicAdd(&cnt_out[src[e]], 1);
    atomicAdd(&cnt_in[dst[e]], 1);
  }
}

__global__ void k_norms(const int* __restrict__ cnt_out, const int* __restrict__ cnt_in,
                        float* norm_out, float* norm_in, int N){
  int n = blockIdx.x*blockDim.x + threadIdx.x;
  if (n < N){
    norm_out[n] = rsqrtf((float)max(cnt_out[n], 1));
    norm_in[n]  = rsqrtf((float)max(cnt_in[n], 1));
  }
}

__global__ void __launch_bounds__(1024) k_scan(const int* __restrict__ cnt_in,
                                               int* row_ptr, int* cursor, int N){
  __shared__ int sm[1024];
  __shared__ int carry_s;
  if (threadIdx.x == 0) carry_s = 0;
  __syncthreads();
  for (int base = 0; base < N; base += 1024){
    int i = base + threadIdx.x;
    int v = (i < N) ? cnt_in[i] : 0;
    sm[threadIdx.x] = v;
    __syncthreads();
    for (int off = 1; off < 1024; off <<= 1){
      int tv = (threadIdx.x >= off) ? sm[threadIdx.x - off] : 0;
      __syncthreads();
      sm[threadIdx.x] += tv;
      __syncthreads();
    }
    int excl = sm[threadIdx.x] - v;
    if (i < N){ row_ptr[i] = carry_s + excl; cursor[i] = carry_s + excl; }
    __syncthreads();
    if (threadIdx.x == 0) carry_s += sm[1023];
    __syncthreads();
  }
  if (threadIdx.x == 0) row_ptr[N] = carry_s;
}

__global__ void k_fill(const int* __restrict__ src, const int* __restrict__ dst,
                       int* cursor, int* es, int E){
  int e = blockIdx.x*blockDim.x + threadIdx.x;
  if (e < E){
    int p = atomicAdd(&cursor[dst[e]], 1);
    es[p] = src[e];
  }
}

// ---------------- gconv1 ----------------

__global__ void k_fn(const float* __restrict__ feat, const float* __restrict__ norm_out,
                     float* __restrict__ fn, int N){
  int n = blockIdx.x*blockDim.x + threadIdx.x;
  int t = blockIdx.y;
  if (n < N) fn[(size_t)t*N + n] = feat[(size_t)t*N + n] * norm_out[n];
}

// x1 = norm_in[n] * sum_e fn[src]; h1s[t][n][j] = silu(x1*W1[j]+b1[j]) * norm_out[n]  (bf16)
__global__ void k_gconv1(const float* __restrict__ fn, const int* __restrict__ row_ptr,
                         const int* __restrict__ es, const float* __restrict__ norm_in,
                         const float* __restrict__ norm_out,
                         const float* __restrict__ W1, const float* __restrict__ b1,
                         ushort* __restrict__ h1s, int N){
  int n = blockIdx.x*blockDim.x + threadIdx.x;
  int t = blockIdx.y;
  if (n >= N) return;
  const float* fnp = fn + (size_t)t*N;
  int s = row_ptr[n], epd = row_ptr[n+1];
  float acc = 0.f;
  for (int e = s; e < epd; ++e) acc += fnp[es[e]];
  float x1 = acc * norm_in[n];
  float no = norm_out[n];
  float hbuf[32];
  #pragma unroll
  for (int j = 0; j < 32; ++j){
    hbuf[j] = silu_f(fmaf(x1, W1[j], b1[j])) * no;
  }
  uint w[16];
  #pragma unroll
  for (int q = 0; q < 16; ++q)
    w[q] = (uint)f2bf(hbuf[2*q]) | ((uint)f2bf(hbuf[2*q+1]) << 16);
  uint4* dp = (uint4*)(h1s + ((size_t)t*N + n)*32);
  dp[0] = make_uint4(w[0],  w[1],  w[2],  w[3]);
  dp[1] = make_uint4(w[4],  w[5],  w[6],  w[7]);
  dp[2] = make_uint4(w[8],  w[9],  w[10], w[11]);
  dp[3] = make_uint4(w[12], w[13], w[14], w[15]);
}

// ---------------- gconv2 gather: x2[t][n][j] = norm_in[n] * sum_e h1s[t][es[e]][j] ----------------

__global__ void k_gconv2(const ushort* __restrict__ h1s, const int* __restrict__ row_ptr,
                         const int* __restrict__ es, const float* __restrict__ norm_in,
                         ushort* __restrict__ x2, int N){
  int t = blockIdx.y;
  int j = threadIdx.x & 31;
  int n = blockIdx.x*8 + (threadIdx.x >> 5);   // N % 8 == 0
  const ushort* h1p = h1s + (size_t)t*N*32;
  int s = row_ptr[n], epd = row_ptr[n+1];
  float acc = 0.f;
  for (int e = s; e < epd; ++e){
    int sn = es[e];
    acc += bf2f(h1p[(size_t)sn*32 + j]);
  }
  x2[((size_t)t*N + n)*32 + j] = f2bf(acc * norm_in[n]);
}

// ---------------- linear 32->128 + silu, PHASE 0: gates, PHASE 1: weighted pool ----------------

template<int PHASE>
__global__ void k_linear(const ushort* __restrict__ x2, const float* __restrict__ W2,
                         const float* __restrict__ b2, const float* __restrict__ gate_w,
                         const float* __restrict__ gate_b,
                         float* __restrict__ gates, const float* __restrict__ mz,
                         float* __restrict__ pooled, int N){
  __shared__ float w2s[32*128];
  __shared__ float x2s[16*32];
  __shared__ float b2s[128];
  __shared__ float gws[128];
  __shared__ float pool_s[128];
  __shared__ float wn_s[16];
  int tid = threadIdx.x;
  int t = blockIdx.y;
  int nb = blockIdx.x * 16;                    // N % 16 == 0
  for (int i = tid; i < 4096; i += 256) w2s[i] = W2[i];
  if (tid < 128){
    b2s[tid] = b2[tid];
    gws[tid] = gate_w[tid];
    if (PHASE == 1) pool_s[tid] = 0.f;
  }
  const ushort* xp = x2 + ((size_t)t*N + nb)*32;
  for (int i = tid; i < 512; i += 256) x2s[i] = bf2f(xp[i]);
  if (PHASE == 1 && tid < 16){
    float m = mz[2*t], invZ = mz[2*t+1];
    wn_s[tid] = expf(gates[(size_t)t*N + nb + tid] - m) * invZ;
  }
  __syncthreads();
  int nl = tid >> 4;      // 0..15 local node
  int kl = tid & 15;      // k = kl + i*16
  float acc[8];
  #pragma unroll
  for (int i = 0; i < 8; ++i) acc[i] = b2s[kl + i*16];
  #pragma unroll 4
  for (int jj = 0; jj < 32; ++jj){
    float xv = x2s[nl*32 + jj];
    #pragma unroll
    for (int i = 0; i < 8; ++i) acc[i] = fmaf(xv, w2s[jj*128 + kl + i*16], acc[i]);
  }
  if (PHASE == 0){
    float gp = 0.f;
    #pragma unroll
    for (int i = 0; i < 8; ++i){ float h = silu_f(acc[i]); gp += h * gws[kl + i*16]; }
    gp += __shfl_xor(gp, 1);
    gp += __shfl_xor(gp, 2);
    gp += __shfl_xor(gp, 4);
    gp += __shfl_xor(gp, 8);
    if (kl == 0) gates[(size_t)t*N + nb + nl] = gp + gate_b[0];
  } else {
    float w = wn_s[nl];
    #pragma unroll
    for (int i = 0; i < 8; ++i){ float h = silu_f(acc[i]); atomicAdd(&pool_s[kl + i*16], h*w); }
    __syncthreads();
    if (tid < 128) atomicAdd(&pooled[(size_t)t*HID + tid], pool_s[tid]);
  }
}

// ---------------- softmax stats per frame ----------------

__global__ void k_softmax(const float* __restrict__ gates, float* mz, int N){
  __shared__ float red[256];
  int t = blockIdx.x, tid = threadIdx.x;
  const float* g = gates + (size_t)t*N;
  float mx = -1e30f;
  for (int i = tid; i < N; i += 256) mx = fmaxf(mx, g[i]);
  red[tid] = mx; __syncthreads();
  for (int off = 128; off > 0; off >>= 1){
    if (tid < off) red[tid] = fmaxf(red[tid], red[tid+off]);
    __syncthreads();
  }
  float m = red[0]; __syncthreads();
  float se = 0.f;
  for (int i = tid; i < N; i += 256) se += expf(g[i] - m);
  red[tid] = se; __syncthreads();
  for (int off = 128; off > 0; off >>= 1){
    if (tid < off) red[tid] += red[tid+off];
    __syncthreads();
  }
  if (tid == 0){ mz[2*t] = m; mz[2*t+1] = 1.0f/red[0]; }
}

// ---------------- GRU + head ----------------

__global__ void k_transpose(const float* __restrict__ W, float* __restrict__ WT,
                            int rows /*3H*/, int cols /*H*/){
  int idx = blockIdx.x*blockDim.x + threadIdx.x;  // WT[j*rows + o] = W[o*cols + j]
  if (idx < rows*cols){
    int j = idx / rows;
    int o = idx % rows;
    WT[idx] = W[o*cols + j];
  }
}

__global__ void k_gi(const float* __restrict__ pooled, const float* __restrict__ WT_ih,
                     const float* __restrict__ b_ih, float* __restrict__ gi_all){
  __shared__ float ps[HID];
  int t = blockIdx.x, tid = threadIdx.x;   // 384 threads
  if (tid < HID) ps[tid] = pooled[(size_t)t*HID + tid];
  __syncthreads();
  float acc = b_ih[tid];
  #pragma unroll 4
  for (int j = 0; j < HID; ++j) acc = fmaf(ps[j], WT_ih[j*384 + tid], acc);
  gi_all[t*384 + tid] = acc;
}

__global__ void k_gru(const float* __restrict__ gi_all, const float* __restrict__ WT_hh,
                      const float* __restrict__ b_hh,
                      const float* __restrict__ d1_w, const float* __restrict__ d1_b,
                      const float* __restrict__ d2_w, const float* __restrict__ d2_b,
                      float* __restrict__ out){
  __shared__ float h_s[HID];
  __shared__ float gh_s[3*HID];
  __shared__ float o1[16];
  int tid = threadIdx.x;  // 384
  if (tid < HID) h_s[tid] = 0.f;
  __syncthreads();
  for (int t = 0; t < T_FRAMES; ++t){
    float acc = b_hh[tid];
    #pragma unroll 4
    for (int j = 0; j < HID; ++j) acc = fmaf(h_s[j], WT_hh[j*384 + tid], acc);
    gh_s[tid] = acc;
    __syncthreads();
    if (tid < HID){
      const float* gi = gi_all + t*384;
      float r  = sigm_f(gi[tid]       + gh_s[tid]);
      float z  = sigm_f(gi[HID+tid]   + gh_s[HID+tid]);
      float nn = tanhf(gi[2*HID+tid] + r*gh_s[2*HID+tid]);
      h_s[tid] = (1.f - z)*nn + z*h_s[tid];
    }
    __syncthreads();
  }
  if (tid < 16){
    float acc = d1_b[tid];
    #pragma unroll 4
    for (int j = 0; j < HID; ++j) acc = fmaf(h_s[j], d1_w[j*16 + tid], acc);
    o1[tid] = silu_f(acc);
  }
  __syncthreads();
  if (tid < 4){
    float acc = d2_b[tid];
    #pragma unroll
    for (int j = 0; j < 16; ++j) acc = fmaf(o1[j], d2_w[j*4 + tid], acc);
    out[tid] = sigm_f(silu_f(acc));
  }
}

// ---------------- launch ----------------

extern "C" void kernel_launch(void* const* d_in, const int* in_sizes, int n_in,
                              void* d_out, int out_size, void* d_ws, size_t ws_size,
                              hipStream_t stream){
  const float* features = (const float*)d_in[0];
  const int*   src      = (const int*)  d_in[1];
  const int*   dst      = (const int*)  d_in[2];
  const float* W1       = (const float*)d_in[3];
  const float* b1       = (const float*)d_in[4];
  const float* W2       = (const float*)d_in[5];
  const float* b2       = (const float*)d_in[6];
  const float* gate_w   = (const float*)d_in[7];
  const float* gate_b   = (const float*)d_in[8];
  const float* W_ih     = (const float*)d_in[9];
  const float* W_hh     = (const float*)d_in[10];
  const float* b_ih     = (const float*)d_in[11];
  const float* b_hh     = (const float*)d_in[12];
  const float* d1_w     = (const float*)d_in[13];
  const float* d1_b     = (const float*)d_in[14];
  const float* d2_w     = (const float*)d_in[15];
  const float* d2_b     = (const float*)d_in[16];
  float* out = (float*)d_out;

  const int N = NNODES, E = NEDGES, T = T_FRAMES;

  char* base = (char*)d_ws;
  size_t off = 0;
  auto alloc = [&](size_t bytes)->void*{
    void* p = base + off;
    off = (off + bytes + 255) & ~(size_t)255;
    return p;
  };
  int*    cnt_out = (int*)   alloc((size_t)N*4);
  int*    cnt_in  = (int*)   alloc((size_t)N*4);
  int*    row_ptr = (int*)   alloc((size_t)(N+1)*4);
  int*    cursor  = (int*)   alloc((size_t)N*4);
  float*  norm_o  = (float*) alloc((size_t)N*4);
  float*  norm_i  = (float*) alloc((size_t)N*4);
  int*    es      = (int*)   alloc((size_t)E*4);
  float*  fn      = (float*) alloc((size_t)T*N*4);
  ushort* h1s     = (ushort*)alloc((size_t)T*N*32*2);
  ushort* x2      = (ushort*)alloc((size_t)T*N*32*2);
  float*  gates   = (float*) alloc((size_t)T*N*4);
  float*  mz      = (float*) alloc((size_t)T*2*4);
  float*  pooled  = (float*) alloc((size_t)T*HID*4);
  float*  gi_all  = (float*) alloc((size_t)T*3*HID*4);
  float*  WT_ih   = (float*) alloc((size_t)3*HID*HID*4);
  float*  WT_hh   = (float*) alloc((size_t)3*HID*HID*4);
  (void)ws_size; (void)in_sizes; (void)n_in; (void)out_size;

  hipMemsetAsync(cnt_out, 0, (size_t)N*4, stream);
  hipMemsetAsync(cnt_in,  0, (size_t)N*4, stream);
  hipMemsetAsync(pooled,  0, (size_t)T*HID*4, stream);

  k_degree<<<(E+255)/256, 256, 0, stream>>>(src, dst, cnt_out, cnt_in, E);
  k_norms <<<(N+255)/256, 256, 0, stream>>>(cnt_out, cnt_in, norm_o, norm_i, N);
  k_scan  <<<1, 1024, 0, stream>>>(cnt_in, row_ptr, cursor, N);
  k_fill  <<<(E+255)/256, 256, 0, stream>>>(src, dst, cursor, es, E);

  k_fn    <<<dim3((N+255)/256, T), 256, 0, stream>>>(features, norm_o, fn, N);
  k_gconv1<<<dim3((N+255)/256, T), 256, 0, stream>>>(fn, row_ptr, es, norm_i, norm_o, W1, b1, h1s, N);
  k_gconv2<<<dim3(N/8, T), 256, 0, stream>>>(h1s, row_ptr, es, norm_i, x2, N);

  k_linear<0><<<dim3(N/16, T), 256, 0, stream>>>(x2, W2, b2, gate_w, gate_b, gates, mz, pooled, N);
  k_softmax  <<<T, 256, 0, stream>>>(gates, mz, N);
  k_linear<1><<<dim3(N/16, T), 256, 0, stream>>>(x2, W2, b2, gate_w, gate_b, gates, mz, pooled, N);

  k_transpose<<<(3*HID*HID+255)/256, 256, 0, stream>>>(W_ih, WT_ih, 3*HID, HID);
  k_transpose<<<(3*HID*HID+255)/256, 256, 0, stream>>>(W_hh, WT_hh, 3*HID, HID);
  k_gi <<<T, 3*HID, 0, stream>>>(pooled, WT_ih, b_ih, gi_all);
  k_gru<<<1, 3*HID, 0, stream>>>(gi_all, WT_hh, b_hh, d1_w, d1_b, d2_w, d2_b, out);
}

// Round 2
// 579.855 us; speedup vs baseline: 1.5704x; 1.5704x over previous
//
#include <hip/hip_runtime.h>
#include <stdint.h>

#define T_FRAMES 32
#define NNODES 10000
#define NEDGES 160000
#define HID 128

typedef short v8s __attribute__((ext_vector_type(8)));
typedef float v4f __attribute__((ext_vector_type(4)));

static __device__ __forceinline__ ushort f2bf(float f){
  uint32_t u = __float_as_uint(f);
  u += 0x7FFFu + ((u >> 16) & 1u);
  return (ushort)(u >> 16);
}
static __device__ __forceinline__ float bf2f(ushort h){
  return __uint_as_float(((uint32_t)h) << 16);
}
static __device__ __forceinline__ float silu_f(float x){
  return x / (1.0f + expf(-x));
}
static __device__ __forceinline__ float sigm_f(float x){
  return 1.0f / (1.0f + expf(-x));
}

// ---------------- degree / norms / CSR build ----------------

__global__ void k_degree(const int* __restrict__ src, const int* __restrict__ dst,
                         int* cnt_out, int* cnt_in, int E){
  int e = blockIdx.x*blockDim.x + threadIdx.x;
  if (e < E){
    atomicAdd(&cnt_out[src[e]], 1);
    atomicAdd(&cnt_in[dst[e]], 1);
  }
}

__global__ void k_norms(const int* __restrict__ cnt_out, const int* __restrict__ cnt_in,
                        float* norm_out, float* norm_in, int N){
  int n = blockIdx.x*blockDim.x + threadIdx.x;
  if (n < N){
    norm_out[n] = rsqrtf((float)max(cnt_out[n], 1));
    norm_in[n]  = rsqrtf((float)max(cnt_in[n], 1));
  }
}

__global__ void __launch_bounds__(1024) k_scan(const int* __restrict__ cnt_in,
                                               int* row_ptr, int* cursor, int N){
  __shared__ int sm[1024];
  __shared__ int carry_s;
  if (threadIdx.x == 0) carry_s = 0;
  __syncthreads();
  for (int base = 0; base < N; base += 1024){
    int i = base + threadIdx.x;
    int v = (i < N) ? cnt_in[i] : 0;
    sm[threadIdx.x] = v;
    __syncthreads();
    for (int off = 1; off < 1024; off <<= 1){
      int tv = (threadIdx.x >= off) ? sm[threadIdx.x - off] : 0;
      __syncthreads();
      sm[threadIdx.x] += tv;
      __syncthreads();
    }
    int excl = sm[threadIdx.x] - v;
    if (i < N){ row_ptr[i] = carry_s + excl; cursor[i] = carry_s + excl; }
    __syncthreads();
    if (threadIdx.x == 0) carry_s += sm[1023];
    __syncthreads();
  }
  if (threadIdx.x == 0) row_ptr[N] = carry_s;
}

__global__ void k_fill(const int* __restrict__ src, const int* __restrict__ dst,
                       int* cursor, int* es, int E){
  int e = blockIdx.x*blockDim.x + threadIdx.x;
  if (e < E){
    int p = atomicAdd(&cursor[dst[e]], 1);
    es[p] = src[e];
  }
}

// ---------------- gconv1 ----------------

__global__ void k_fn(const float* __restrict__ feat, const float* __restrict__ norm_out,
                     float* __restrict__ fn, int N){
  int n = blockIdx.x*blockDim.x + threadIdx.x;
  int t = blockIdx.y;
  if (n < N) fn[(size_t)t*N + n] = feat[(size_t)t*N + n] * norm_out[n];
}

// x1 = norm_in[n] * sum_e fn[src]; h1s[t][n][j] = silu(x1*W1[j]+b1[j]) * norm_out[n]  (bf16)
__global__ void k_gconv1(const float* __restrict__ fn, const int* __restrict__ row_ptr,
                         const int* __restrict__ es, const float* __restrict__ norm_in,
                         const float* __restrict__ norm_out,
                         const float* __restrict__ W1, const float* __restrict__ b1,
                         ushort* __restrict__ h1s, int N){
  int n = blockIdx.x*blockDim.x + threadIdx.x;
  int t = blockIdx.y;
  if (n >= N) return;
  const float* fnp = fn + (size_t)t*N;
  int s = row_ptr[n], epd = row_ptr[n+1];
  float acc = 0.f;
  for (int e = s; e < epd; ++e) acc += fnp[es[e]];
  float x1 = acc * norm_in[n];
  float no = norm_out[n];
  float hbuf[32];
  #pragma unroll
  for (int j = 0; j < 32; ++j){
    hbuf[j] = silu_f(fmaf(x1, W1[j], b1[j])) * no;
  }
  uint w[16];
  #pragma unroll
  for (int q = 0; q < 16; ++q)
    w[q] = (uint)f2bf(hbuf[2*q]) | ((uint)f2bf(hbuf[2*q+1]) << 16);
  uint4* dp = (uint4*)(h1s + ((size_t)t*N + n)*32);
  dp[0] = make_uint4(w[0],  w[1],  w[2],  w[3]);
  dp[1] = make_uint4(w[4],  w[5],  w[6],  w[7]);
  dp[2] = make_uint4(w[8],  w[9],  w[10], w[11]);
  dp[3] = make_uint4(w[12], w[13], w[14], w[15]);
}

// ---------------- gconv2 gather: x2[t][n][j] = norm_in[n] * sum_e h1s[t][es[e]][j] ----------------

__global__ void k_gconv2(const ushort* __restrict__ h1s, const int* __restrict__ row_ptr,
                         const int* __restrict__ es, const float* __restrict__ norm_in,
                         ushort* __restrict__ x2, int N){
  int t = blockIdx.y;
  int j = threadIdx.x & 31;
  int n = blockIdx.x*8 + (threadIdx.x >> 5);   // N % 8 == 0
  const ushort* h1p = h1s + (size_t)t*N*32;
  int s = row_ptr[n], epd = row_ptr[n+1];
  float acc = 0.f;
  for (int e = s; e < epd; ++e){
    int sn = es[e];
    acc += bf2f(h1p[(size_t)sn*32 + j]);
  }
  x2[((size_t)t*N + n)*32 + j] = f2bf(acc * norm_in[n]);
}

// ---------------- W2 -> bf16 MFMA B-fragments ----------------
// W2F[i][l][j] (i=frag 0..7, l=lane 0..63, j=0..7): W2bf[k=(l>>4)*8+j][i*16 + (l&15)]

__global__ void k_w2frag(const float* __restrict__ W2, ushort* __restrict__ W2F){
  int tid = blockIdx.x*blockDim.x + threadIdx.x;  // 0..4095
  int j = tid & 7, l = (tid >> 3) & 63, i = tid >> 9;
  int g = l >> 4, n = l & 15;
  W2F[tid] = f2bf(W2[(g*8 + j)*128 + i*16 + n]);
}

// ---------------- linear 32->128 + silu via MFMA ----------------
// PHASE 0: gates[t][n] = silu(x2@W2+b2) . gate_w + gate_b
// PHASE 1: pooled[t][:] += softmax-weight[n] * silu(x2@W2+b2)

template<int PHASE>
__global__ void __launch_bounds__(256) k_linear_mfma(
    const ushort* __restrict__ x2, const ushort* __restrict__ W2F,
    const float* __restrict__ b2, const float* __restrict__ gate_w,
    const float* __restrict__ gate_b,
    float* __restrict__ gates, const float* __restrict__ mz,
    float* __restrict__ pooled, int N){
  __shared__ float pool_s[128];
  int t = blockIdx.y;
  int tid = threadIdx.x;
  int wave = tid >> 6, lane = tid & 63;
  int g = lane >> 4, n = lane & 15;
  if (PHASE == 1){
    if (tid < 128) pool_s[tid] = 0.f;
    __syncthreads();
  }
  int tile = blockIdx.x*4 + wave;          // 16-node tile; N==625*16 so tiles are full
  bool active = (tile*16 < N);

  const v8s* W2Fv = (const v8s*)W2F;
  v8s bfrag[8];
  #pragma unroll
  for (int i = 0; i < 8; ++i) bfrag[i] = W2Fv[i*64 + lane];
  v4f acc[8];
  #pragma unroll
  for (int i = 0; i < 8; ++i){
    float bv = b2[i*16 + n];
    acc[i] = (v4f){bv, bv, bv, bv};
  }
  if (active){
    int nb = tile*16;
    const v8s* ap = (const v8s*)(x2 + ((size_t)t*N + nb)*32);
    v8s a = ap[(lane & 15)*4 + g];   // node row (lane&15), k-chunk g*8..g*8+7
    #pragma unroll
    for (int i = 0; i < 8; ++i)
      acc[i] = __builtin_amdgcn_mfma_f32_16x16x32_bf16(a, bfrag[i], acc[i], 0, 0, 0);
  }
  // C/D layout: value (i,r) = h[node nb + g*4 + r][col i*16 + n]
  if (PHASE == 0){
    if (active){
      float gw8[8];
      #pragma unroll
      for (int i = 0; i < 8; ++i) gw8[i] = gate_w[i*16 + n];
      float gp[4] = {0.f, 0.f, 0.f, 0.f};
      #pragma unroll
      for (int i = 0; i < 8; ++i){
        #pragma unroll
        for (int r = 0; r < 4; ++r) gp[r] += silu_f(acc[i][r]) * gw8[i];
      }
      #pragma unroll
      for (int m = 1; m < 16; m <<= 1){
        #pragma unroll
        for (int r = 0; r < 4; ++r) gp[r] += __shfl_xor(gp[r], m);
      }
      if (n == 0){
        int nb = tile*16;
        float gb = gate_b[0];
        #pragma unroll
        for (int r = 0; r < 4; ++r) gates[(size_t)t*N + nb + g*4 + r] = gp[r] + gb;
      }
    }
  } else {
    if (active){
      int nb = tile*16;
      float m0 = mz[2*t], invZ = mz[2*t+1];
      float wn[4];
      #pragma unroll
      for (int r = 0; r < 4; ++r)
        wn[r] = expf(gates[(size_t)t*N + nb + g*4 + r] - m0) * invZ;
      float cs[8];
      #pragma unroll
      for (int i = 0; i < 8; ++i){
        float c = 0.f;
        #pragma unroll
        for (int r = 0; r < 4; ++r) c += silu_f(acc[i][r]) * wn[r];
        c += __shfl_xor(c, 16);
        c += __shfl_xor(c, 32);
        cs[i] = c;
      }
      if (lane < 16){
        #pragma unroll
        for (int i = 0; i < 8; ++i) atomicAdd(&pool_s[i*16 + lane], cs[i]);
      }
    }
    __syncthreads();
    if (tid < 128) atomicAdd(&pooled[(size_t)t*HID + tid], pool_s[tid]);
  }
}

// ---------------- softmax stats per frame ----------------

__global__ void k_softmax(const float* __restrict__ gates, float* mz, int N){
  __shared__ float red[256];
  int t = blockIdx.x, tid = threadIdx.x;
  const float* g = gates + (size_t)t*N;
  float mx = -1e30f;
  for (int i = tid; i < N; i += 256) mx = fmaxf(mx, g[i]);
  red[tid] = mx; __syncthreads();
  for (int off = 128; off > 0; off >>= 1){
    if (tid < off) red[tid] = fmaxf(red[tid], red[tid+off]);
    __syncthreads();
  }
  float m = red[0]; __syncthreads();
  float se = 0.f;
  for (int i = tid; i < N; i += 256) se += expf(g[i] - m);
  red[tid] = se; __syncthreads();
  for (int off = 128; off > 0; off >>= 1){
    if (tid < off) red[tid] += red[tid+off];
    __syncthreads();
  }
  if (tid == 0){ mz[2*t] = m; mz[2*t+1] = 1.0f/red[0]; }
}

// ---------------- GRU + head ----------------

__global__ void k_transpose(const float* __restrict__ W, float* __restrict__ WT,
                            int rows /*3H*/, int cols /*H*/){
  int idx = blockIdx.x*blockDim.x + threadIdx.x;  // WT[j*rows + o] = W[o*cols + j]
  if (idx < rows*cols){
    int j = idx / rows;
    int o = idx % rows;
    WT[idx] = W[o*cols + j];
  }
}

__global__ void k_gi(const float* __restrict__ pooled, const float* __restrict__ WT_ih,
                     const float* __restrict__ b_ih, float* __restrict__ gi_all){
  __shared__ float ps[HID];
  int t = blockIdx.x, tid = threadIdx.x;   // 384 threads
  if (tid < HID) ps[tid] = pooled[(size_t)t*HID + tid];
  __syncthreads();
  float acc = b_ih[tid];
  #pragma unroll 4
  for (int j = 0; j < HID; ++j) acc = fmaf(ps[j], WT_ih[j*384 + tid], acc);
  gi_all[t*384 + tid] = acc;
}

__global__ void k_gru(const float* __restrict__ gi_all, const float* __restrict__ WT_hh,
                      const float* __restrict__ b_hh,
                      const float* __restrict__ d1_w, const float* __restrict__ d1_b,
                      const float* __restrict__ d2_w, const float* __restrict__ d2_b,
                      float* __restrict__ out){
  __shared__ float h_s[HID];
  __shared__ float gh_s[3*HID];
  __shared__ float o1[16];
  int tid = threadIdx.x;  // 384
  if (tid < HID) h_s[tid] = 0.f;
  __syncthreads();
  for (int t = 0; t < T_FRAMES; ++t){
    float acc = b_hh[tid];
    #pragma unroll 4
    for (int j = 0; j < HID; ++j) acc = fmaf(h_s[j], WT_hh[j*384 + tid], acc);
    gh_s[tid] = acc;
    __syncthreads();
    if (tid < HID){
      const float* gi = gi_all + t*384;
      float r  = sigm_f(gi[tid]       + gh_s[tid]);
      float z  = sigm_f(gi[HID+tid]   + gh_s[HID+tid]);
      float nn = tanhf(gi[2*HID+tid] + r*gh_s[2*HID+tid]);
      h_s[tid] = (1.f - z)*nn + z*h_s[tid];
    }
    __syncthreads();
  }
  if (tid < 16){
    float acc = d1_b[tid];
    #pragma unroll 4
    for (int j = 0; j < HID; ++j) acc = fmaf(h_s[j], d1_w[j*16 + tid], acc);
    o1[tid] = silu_f(acc);
  }
  __syncthreads();
  if (tid < 4){
    float acc = d2_b[tid];
    #pragma unroll
    for (int j = 0; j < 16; ++j) acc = fmaf(o1[j], d2_w[j*4 + tid], acc);
    out[tid] = sigm_f(silu_f(acc));
  }
}

// ---------------- launch ----------------

extern "C" void kernel_launch(void* const* d_in, const int* in_sizes, int n_in,
                              void* d_out, int out_size, void* d_ws, size_t ws_size,
                              hipStream_t stream){
  const float* features = (const float*)d_in[0];
  const int*   src      = (const int*)  d_in[1];
  const int*   dst      = (const int*)  d_in[2];
  const float* W1       = (const float*)d_in[3];
  const float* b1       = (const float*)d_in[4];
  const float* W2       = (const float*)d_in[5];
  const float* b2       = (const float*)d_in[6];
  const float* gate_w   = (const float*)d_in[7];
  const float* gate_b   = (const float*)d_in[8];
  const float* W_ih     = (const float*)d_in[9];
  const float* W_hh     = (const float*)d_in[10];
  const float* b_ih     = (const float*)d_in[11];
  const float* b_hh     = (const float*)d_in[12];
  const float* d1_w     = (const float*)d_in[13];
  const float* d1_b     = (const float*)d_in[14];
  const float* d2_w     = (const float*)d_in[15];
  const float* d2_b     = (const float*)d_in[16];
  float* out = (float*)d_out;

  const int N = NNODES, E = NEDGES, T = T_FRAMES;

  char* base = (char*)d_ws;
  size_t off = 0;
  auto alloc = [&](size_t bytes)->void*{
    void* p = base + off;
    off = (off + bytes + 255) & ~(size_t)255;
    return p;
  };
  int*    cnt_out = (int*)   alloc((size_t)N*4);
  int*    cnt_in  = (int*)   alloc((size_t)N*4);
  int*    row_ptr = (int*)   alloc((size_t)(N+1)*4);
  int*    cursor  = (int*)   alloc((size_t)N*4);
  float*  norm_o  = (float*) alloc((size_t)N*4);
  float*  norm_i  = (float*) alloc((size_t)N*4);
  int*    es      = (int*)   alloc((size_t)E*4);
  float*  fn      = (float*) alloc((size_t)T*N*4);
  ushort* h1s     = (ushort*)alloc((size_t)T*N*32*2);
  ushort* x2      = (ushort*)alloc((size_t)T*N*32*2);
  float*  gates   = (float*) alloc((size_t)T*N*4);
  float*  mz      = (float*) alloc((size_t)T*2*4);
  float*  pooled  = (float*) alloc((size_t)T*HID*4);
  float*  gi_all  = (float*) alloc((size_t)T*3*HID*4);
  float*  WT_ih   = (float*) alloc((size_t)3*HID*HID*4);
  float*  WT_hh   = (float*) alloc((size_t)3*HID*HID*4);
  ushort* W2F     = (ushort*)alloc((size_t)8*64*8*2);
  (void)ws_size; (void)in_sizes; (void)n_in; (void)out_size;

  hipMemsetAsync(cnt_out, 0, (size_t)N*4, stream);
  hipMemsetAsync(cnt_in,  0, (size_t)N*4, stream);
  hipMemsetAsync(pooled,  0, (size_t)T*HID*4, stream);

  k_degree<<<(E+255)/256, 256, 0, stream>>>(src, dst, cnt_out, cnt_in, E);
  k_norms <<<(N+255)/256, 256, 0, stream>>>(cnt_out, cnt_in, norm_o, norm_i, N);
  k_scan  <<<1, 1024, 0, stream>>>(cnt_in, row_ptr, cursor, N);
  k_fill  <<<(E+255)/256, 256, 0, stream>>>(src, dst, cursor, es, E);

  k_fn    <<<dim3((N+255)/256, T), 256, 0, stream>>>(features, norm_o, fn, N);
  k_gconv1<<<dim3((N+255)/256, T), 256, 0, stream>>>(fn, row_ptr, es, norm_i, norm_o, W1, b1, h1s, N);
  k_gconv2<<<dim3(N/8, T), 256, 0, stream>>>(h1s, row_ptr, es, norm_i, x2, N);

  k_w2frag<<<16, 256, 0, stream>>>(W2, W2F);

  const int NT = (N + 15) / 16;           // 625 16-node tiles
  const int GX = (NT + 3) / 4;            // 4 waves (tiles) per block
  k_linear_mfma<0><<<dim3(GX, T), 256, 0, stream>>>(x2, W2F, b2, gate_w, gate_b, gates, mz, pooled, N);
  k_softmax<<<T, 256, 0, stream>>>(gates, mz, N);
  k_linear_mfma<1><<<dim3(GX, T), 256, 0, stream>>>(x2, W2F, b2, gate_w, gate_b, gates, mz, pooled, N);

  k_transpose<<<(3*HID*HID+255)/256, 256, 0, stream>>>(W_ih, WT_ih, 3*HID, HID);
  k_transpose<<<(3*HID*HID+255)/256, 256, 0, stream>>>(W_hh, WT_hh, 3*HID, HID);
  k_gi <<<T, 3*HID, 0, stream>>>(pooled, WT_ih, b_ih, gi_all);
  k_gru<<<1, 3*HID, 0, stream>>>(gi_all, WT_hh, b_hh, d1_w, d1_b, d2_w, d2_b, out);
}

// Round 3
// 392.081 us; speedup vs baseline: 2.3225x; 1.4789x over previous
//
#include <hip/hip_runtime.h>
#include <stdint.h>

#define T_FRAMES 32
#define NNODES 10000
#define NEDGES 160000
#define HID 128

typedef short v8s __attribute__((ext_vector_type(8)));
typedef float v4f __attribute__((ext_vector_type(4)));

static __device__ __forceinline__ ushort f2bf(float f){
  uint32_t u = __float_as_uint(f);
  u += 0x7FFFu + ((u >> 16) & 1u);
  return (ushort)(u >> 16);
}
static __device__ __forceinline__ float bf_lo(uint32_t u){
  return __uint_as_float(u << 16);
}
static __device__ __forceinline__ float bf_hi(uint32_t u){
  return __uint_as_float(u & 0xffff0000u);
}
static __device__ __forceinline__ float silu_f(float x){
  return x / (1.0f + expf(-x));
}
static __device__ __forceinline__ float sigm_f(float x){
  return 1.0f / (1.0f + expf(-x));
}

// ---------------- degree / norms / CSR build ----------------

__global__ void k_degree(const int* __restrict__ src, const int* __restrict__ dst,
                         int* cnt_out, int* cnt_in, int E){
  int e = blockIdx.x*blockDim.x + threadIdx.x;
  if (e < E){
    atomicAdd(&cnt_out[src[e]], 1);
    atomicAdd(&cnt_in[dst[e]], 1);
  }
}

__global__ void k_norms(const int* __restrict__ cnt_out, const int* __restrict__ cnt_in,
                        float* norm_out, float* norm_in, int N){
  int n = blockIdx.x*blockDim.x + threadIdx.x;
  if (n < N){
    norm_out[n] = rsqrtf((float)max(cnt_out[n], 1));
    norm_in[n]  = rsqrtf((float)max(cnt_in[n], 1));
  }
}

__global__ void __launch_bounds__(1024) k_scan(const int* __restrict__ cnt_in,
                                               int* row_ptr, int* cursor, int N){
  __shared__ int sm[1024];
  __shared__ int carry_s;
  if (threadIdx.x == 0) carry_s = 0;
  __syncthreads();
  for (int base = 0; base < N; base += 1024){
    int i = base + threadIdx.x;
    int v = (i < N) ? cnt_in[i] : 0;
    sm[threadIdx.x] = v;
    __syncthreads();
    for (int off = 1; off < 1024; off <<= 1){
      int tv = (threadIdx.x >= off) ? sm[threadIdx.x - off] : 0;
      __syncthreads();
      sm[threadIdx.x] += tv;
      __syncthreads();
    }
    int excl = sm[threadIdx.x] - v;
    if (i < N){ row_ptr[i] = carry_s + excl; cursor[i] = carry_s + excl; }
    __syncthreads();
    if (threadIdx.x == 0) carry_s += sm[1023];
    __syncthreads();
  }
  if (threadIdx.x == 0) row_ptr[N] = carry_s;
}

__global__ void k_fill(const int* __restrict__ src, const int* __restrict__ dst,
                       int* cursor, int* es, int E){
  int e = blockIdx.x*blockDim.x + threadIdx.x;
  if (e < E){
    int p = atomicAdd(&cursor[dst[e]], 1);
    es[p] = src[e];
  }
}

// ---------------- transpose features -> node-major, pre-scaled by norm_out ----------------
// fnT[n][t] = features[t][n] * norm_out[n]

__global__ void __launch_bounds__(256) k_fnT(const float* __restrict__ feat,
                                             const float* __restrict__ norm_o,
                                             float* __restrict__ fnT, int N){
  __shared__ float sm[32][65];
  int n0 = blockIdx.x*64;
  int tid = threadIdx.x;
  for (int idx = tid; idx < 2048; idx += 256){
    int t = idx >> 6, i = idx & 63;
    int n = n0 + i;
    sm[t][i] = (n < N) ? feat[(size_t)t*N + n] : 0.f;
  }
  __syncthreads();
  for (int idx = tid; idx < 2048; idx += 256){
    int i = idx >> 5, t = idx & 31;
    int n = n0 + i;
    if (n < N) fnT[(size_t)n*32 + t] = sm[t][i] * norm_o[n];
  }
}

// ---------------- gconv1 (node-major): one wave per node ----------------
// x1[t] = norm_in[n] * sum_e fnT[es[e]][t]
// h1s[n][t][j] = silu(x1[t]*W1[j]+b1[j]) * norm_out[n]   (bf16, row = 2KB)

__global__ void __launch_bounds__(256) k_gconv1_nm(
    const float* __restrict__ fnT, const int* __restrict__ row_ptr,
    const int* __restrict__ es, const float* __restrict__ norm_in,
    const float* __restrict__ norm_out,
    const float* __restrict__ W1, const float* __restrict__ b1,
    ushort* __restrict__ h1s, int N){
  __shared__ float w1s[32], b1s[32];
  int tid = threadIdx.x;
  if (tid < 32){ w1s[tid] = W1[tid]; b1s[tid] = b1[tid]; }
  __syncthreads();
  int n = blockIdx.x*4 + (tid >> 6);          // N % 4 == 0
  int lane = tid & 63;
  int ep = lane >> 5, t = lane & 31;
  int s = row_ptr[n], d = row_ptr[n+1];
  float acc = 0.f;
  for (int e = s + ep; e < d; e += 2)
    acc += fnT[(size_t)es[e]*32 + t];
  acc += __shfl_xor(acc, 32);
  float x1 = acc * norm_in[n];                // valid at lanes t and t+32
  float x1p = __shfl(x1, lane >> 1);          // lane l gets x1[t = l>>1]
  float no = norm_out[n];
  int j0 = (lane & 1) * 16;
  uint w[8];
  #pragma unroll
  for (int q = 0; q < 8; ++q){
    float h0 = silu_f(fmaf(x1p, w1s[j0+2*q],   b1s[j0+2*q]))   * no;
    float h1 = silu_f(fmaf(x1p, w1s[j0+2*q+1], b1s[j0+2*q+1])) * no;
    w[q] = (uint)f2bf(h0) | ((uint)f2bf(h1) << 16);
  }
  uint4* dp = (uint4*)(h1s + (size_t)n*1024 + lane*16);
  dp[0] = make_uint4(w[0], w[1], w[2], w[3]);
  dp[1] = make_uint4(w[4], w[5], w[6], w[7]);
}

// ---------------- gconv2 (node-major): one wave per node ----------------
// x2[n][t][j] = norm_in[n] * sum_e h1s[es[e]][t][j]  — each edge = 2KB coalesced read

__global__ void __launch_bounds__(256) k_gconv2_nm(
    const ushort* __restrict__ h1s, const int* __restrict__ row_ptr,
    const int* __restrict__ es, const float* __restrict__ norm_in,
    ushort* __restrict__ x2, int N){
  int tid = threadIdx.x;
  int n = blockIdx.x*4 + (tid >> 6);
  int lane = tid & 63;
  int s = row_ptr[n], d = row_ptr[n+1];
  float acc[16];
  #pragma unroll
  for (int i = 0; i < 16; ++i) acc[i] = 0.f;

  #define ACC_U4(v, base) do { \
    acc[(base)+0] += bf_lo((v).x); acc[(base)+1] += bf_hi((v).x); \
    acc[(base)+2] += bf_lo((v).y); acc[(base)+3] += bf_hi((v).y); \
    acc[(base)+4] += bf_lo((v).z); acc[(base)+5] += bf_hi((v).z); \
    acc[(base)+6] += bf_lo((v).w); acc[(base)+7] += bf_hi((v).w); \
  } while(0)

  int e = s;
  for (; e + 1 < d; e += 2){
    const uint4* p0 = (const uint4*)(h1s + (size_t)es[e]  *1024) + lane*2;
    const uint4* p1 = (const uint4*)(h1s + (size_t)es[e+1]*1024) + lane*2;
    uint4 a0 = p0[0], a1 = p0[1];
    uint4 c0 = p1[0], c1 = p1[1];
    ACC_U4(a0, 0); ACC_U4(a1, 8);
    ACC_U4(c0, 0); ACC_U4(c1, 8);
  }
  if (e < d){
    const uint4* p0 = (const uint4*)(h1s + (size_t)es[e]*1024) + lane*2;
    uint4 a0 = p0[0], a1 = p0[1];
    ACC_U4(a0, 0); ACC_U4(a1, 8);
  }
  #undef ACC_U4

  float ni = norm_in[n];
  uint w[8];
  #pragma unroll
  for (int q = 0; q < 8; ++q)
    w[q] = (uint)f2bf(acc[2*q]*ni) | ((uint)f2bf(acc[2*q+1]*ni) << 16);
  uint4* dp = (uint4*)(x2 + (size_t)n*1024 + lane*16);
  dp[0] = make_uint4(w[0], w[1], w[2], w[3]);
  dp[1] = make_uint4(w[4], w[5], w[6], w[7]);
}

// ---------------- W2 -> bf16 MFMA B-fragments ----------------
// W2F[i][l][j] (i=frag 0..7, l=lane 0..63, j=0..7): W2bf[k=(l>>4)*8+j][i*16 + (l&15)]

__global__ void k_w2frag(const float* __restrict__ W2, ushort* __restrict__ W2F){
  int tid = blockIdx.x*blockDim.x + threadIdx.x;  // 0..4095
  int j = tid & 7, l = (tid >> 3) & 63, i = tid >> 9;
  int g = l >> 4, n = l & 15;
  W2F[tid] = f2bf(W2[(g*8 + j)*128 + i*16 + n]);
}

// ---------------- linear 32->128 + silu via MFMA (x2 node-major) ----------------
// PHASE 0: gates[t][n] = silu(x2@W2+b2) . gate_w + gate_b
// PHASE 1: pooled[t][:] += softmax-weight[n] * silu(x2@W2+b2)

template<int PHASE>
__global__ void __launch_bounds__(256) k_linear_mfma(
    const ushort* __restrict__ x2, const ushort* __restrict__ W2F,
    const float* __restrict__ b2, const float* __restrict__ gate_w,
    const float* __restrict__ gate_b,
    float* __restrict__ gates, const float* __restrict__ mz,
    float* __restrict__ pooled, int N){
  __shared__ float pool_s[128];
  int t = blockIdx.y;
  int tid = threadIdx.x;
  int wave = tid >> 6, lane = tid & 63;
  int g = lane >> 4, n = lane & 15;
  if (PHASE == 1){
    if (tid < 128) pool_s[tid] = 0.f;
    __syncthreads();
  }
  int tile = blockIdx.x*4 + wave;          // 16-node tile; N = 625*16
  bool active = (tile*16 < N);

  const v8s* W2Fv = (const v8s*)W2F;
  v8s bfrag[8];
  #pragma unroll
  for (int i = 0; i < 8; ++i) bfrag[i] = W2Fv[i*64 + lane];
  v4f acc[8];
  #pragma unroll
  for (int i = 0; i < 8; ++i){
    float bv = b2[i*16 + n];
    acc[i] = (v4f){bv, bv, bv, bv};
  }
  if (active){
    int nb = tile*16;
    // x2 element index: node*1024 + t*32 + j ; lane reads node nb+(lane&15), k-chunk g*8..
    const v8s* ap = (const v8s*)(x2 + (size_t)(nb + (lane & 15))*1024 + t*32);
    v8s a = ap[g];
    #pragma unroll
    for (int i = 0; i < 8; ++i)
      acc[i] = __builtin_amdgcn_mfma_f32_16x16x32_bf16(a, bfrag[i], acc[i], 0, 0, 0);
  }
  // C/D layout: value (i,r) = h[node nb + g*4 + r][col i*16 + n]
  if (PHASE == 0){
    if (active){
      float gw8[8];
      #pragma unroll
      for (int i = 0; i < 8; ++i) gw8[i] = gate_w[i*16 + n];
      float gp[4] = {0.f, 0.f, 0.f, 0.f};
      #pragma unroll
      for (int i = 0; i < 8; ++i){
        #pragma unroll
        for (int r = 0; r < 4; ++r) gp[r] += silu_f(acc[i][r]) * gw8[i];
      }
      #pragma unroll
      for (int m = 1; m < 16; m <<= 1){
        #pragma unroll
        for (int r = 0; r < 4; ++r) gp[r] += __shfl_xor(gp[r], m);
      }
      if (n == 0){
        int nb = tile*16;
        float gb = gate_b[0];
        #pragma unroll
        for (int r = 0; r < 4; ++r) gates[(size_t)t*N + nb + g*4 + r] = gp[r] + gb;
      }
    }
  } else {
    if (active){
      int nb = tile*16;
      float m0 = mz[2*t], invZ = mz[2*t+1];
      float wn[4];
      #pragma unroll
      for (int r = 0; r < 4; ++r)
        wn[r] = expf(gates[(size_t)t*N + nb + g*4 + r] - m0) * invZ;
      float cs[8];
      #pragma unroll
      for (int i = 0; i < 8; ++i){
        float c = 0.f;
        #pragma unroll
        for (int r = 0; r < 4; ++r) c += silu_f(acc[i][r]) * wn[r];
        c += __shfl_xor(c, 16);
        c += __shfl_xor(c, 32);
        cs[i] = c;
      }
      if (lane < 16){
        #pragma unroll
        for (int i = 0; i < 8; ++i) atomicAdd(&pool_s[i*16 + lane], cs[i]);
      }
    }
    __syncthreads();
    if (tid < 128) atomicAdd(&pooled[(size_t)t*HID + tid], pool_s[tid]);
  }
}

// ---------------- softmax stats per frame ----------------

__global__ void k_softmax(const float* __restrict__ gates, float* mz, int N){
  __shared__ float red[256];
  int t = blockIdx.x, tid = threadIdx.x;
  const float* g = gates + (size_t)t*N;
  float mx = -1e30f;
  for (int i = tid; i < N; i += 256) mx = fmaxf(mx, g[i]);
  red[tid] = mx; __syncthreads();
  for (int off = 128; off > 0; off >>= 1){
    if (tid < off) red[tid] = fmaxf(red[tid], red[tid+off]);
    __syncthreads();
  }
  float m = red[0]; __syncthreads();
  float se = 0.f;
  for (int i = tid; i < N; i += 256) se += expf(g[i] - m);
  red[tid] = se; __syncthreads();
  for (int off = 128; off > 0; off >>= 1){
    if (tid < off) red[tid] += red[tid+off];
    __syncthreads();
  }
  if (tid == 0){ mz[2*t] = m; mz[2*t+1] = 1.0f/red[0]; }
}

// ---------------- GRU + head ----------------

__global__ void k_transpose(const float* __restrict__ W, float* __restrict__ WT,
                            int rows /*3H*/, int cols /*H*/){
  int idx = blockIdx.x*blockDim.x + threadIdx.x;  // WT[j*rows + o] = W[o*cols + j]
  if (idx < rows*cols){
    int j = idx / rows;
    int o = idx % rows;
    WT[idx] = W[o*cols + j];
  }
}

__global__ void k_gi(const float* __restrict__ pooled, const float* __restrict__ WT_ih,
                     const float* __restrict__ b_ih, float* __restrict__ gi_all){
  __shared__ float ps[HID];
  int t = blockIdx.x, tid = threadIdx.x;   // 384 threads
  if (tid < HID) ps[tid] = pooled[(size_t)t*HID + tid];
  __syncthreads();
  float acc = b_ih[tid];
  #pragma unroll 4
  for (int j = 0; j < HID; ++j) acc = fmaf(ps[j], WT_ih[j*384 + tid], acc);
  gi_all[t*384 + tid] = acc;
}

__global__ void k_gru(const float* __restrict__ gi_all, const float* __restrict__ WT_hh,
                      const float* __restrict__ b_hh,
                      const float* __restrict__ d1_w, const float* __restrict__ d1_b,
                      const float* __restrict__ d2_w, const float* __restrict__ d2_b,
                      float* __restrict__ out){
  __shared__ float h_s[HID];
  __shared__ float gh_s[3*HID];
  __shared__ float o1[16];
  int tid = threadIdx.x;  // 384
  if (tid < HID) h_s[tid] = 0.f;
  __syncthreads();
  for (int t = 0; t < T_FRAMES; ++t){
    float acc = b_hh[tid];
    #pragma unroll 4
    for (int j = 0; j < HID; ++j) acc = fmaf(h_s[j], WT_hh[j*384 + tid], acc);
    gh_s[tid] = acc;
    __syncthreads();
    if (tid < HID){
      const float* gi = gi_all + t*384;
      float r  = sigm_f(gi[tid]       + gh_s[tid]);
      float z  = sigm_f(gi[HID+tid]   + gh_s[HID+tid]);
      float nn = tanhf(gi[2*HID+tid] + r*gh_s[2*HID+tid]);
      h_s[tid] = (1.f - z)*nn + z*h_s[tid];
    }
    __syncthreads();
  }
  if (tid < 16){
    float acc = d1_b[tid];
    #pragma unroll 4
    for (int j = 0; j < HID; ++j) acc = fmaf(h_s[j], d1_w[j*16 + tid], acc);
    o1[tid] = silu_f(acc);
  }
  __syncthreads();
  if (tid < 4){
    float acc = d2_b[tid];
    #pragma unroll
    for (int j = 0; j < 16; ++j) acc = fmaf(o1[j], d2_w[j*4 + tid], acc);
    out[tid] = sigm_f(silu_f(acc));
  }
}

// ---------------- launch ----------------

extern "C" void kernel_launch(void* const* d_in, const int* in_sizes, int n_in,
                              void* d_out, int out_size, void* d_ws, size_t ws_size,
                              hipStream_t stream){
  const float* features = (const float*)d_in[0];
  const int*   src      = (const int*)  d_in[1];
  const int*   dst      = (const int*)  d_in[2];
  const float* W1       = (const float*)d_in[3];
  const float* b1       = (const float*)d_in[4];
  const float* W2       = (const float*)d_in[5];
  const float* b2       = (const float*)d_in[6];
  const float* gate_w   = (const float*)d_in[7];
  const float* gate_b   = (const float*)d_in[8];
  const float* W_ih     = (const float*)d_in[9];
  const float* W_hh     = (const float*)d_in[10];
  const float* b_ih     = (const float*)d_in[11];
  const float* b_hh     = (const float*)d_in[12];
  const float* d1_w     = (const float*)d_in[13];
  const float* d1_b     = (const float*)d_in[14];
  const float* d2_w     = (const float*)d_in[15];
  const float* d2_b     = (const float*)d_in[16];
  float* out = (float*)d_out;

  const int N = NNODES, E = NEDGES, T = T_FRAMES;

  char* base = (char*)d_ws;
  size_t off = 0;
  auto alloc = [&](size_t bytes)->void*{
    void* p = base + off;
    off = (off + bytes + 255) & ~(size_t)255;
    return p;
  };
  int*    cnt_out = (int*)   alloc((size_t)N*4);
  int*    cnt_in  = (int*)   alloc((size_t)N*4);
  int*    row_ptr = (int*)   alloc((size_t)(N+1)*4);
  int*    cursor  = (int*)   alloc((size_t)N*4);
  float*  norm_o  = (float*) alloc((size_t)N*4);
  float*  norm_i  = (float*) alloc((size_t)N*4);
  int*    es      = (int*)   alloc((size_t)E*4);
  float*  fnT     = (float*) alloc((size_t)N*T*4);
  ushort* h1s     = (ushort*)alloc((size_t)N*T*32*2);
  ushort* x2      = (ushort*)alloc((size_t)N*T*32*2);
  float*  gates   = (float*) alloc((size_t)T*N*4);
  float*  mz      = (float*) alloc((size_t)T*2*4);
  float*  pooled  = (float*) alloc((size_t)T*HID*4);
  float*  gi_all  = (float*) alloc((size_t)T*3*HID*4);
  float*  WT_ih   = (float*) alloc((size_t)3*HID*HID*4);
  float*  WT_hh   = (float*) alloc((size_t)3*HID*HID*4);
  ushort* W2F     = (ushort*)alloc((size_t)8*64*8*2);
  (void)ws_size; (void)in_sizes; (void)n_in; (void)out_size;

  hipMemsetAsync(cnt_out, 0, (size_t)N*4, stream);
  hipMemsetAsync(cnt_in,  0, (size_t)N*4, stream);
  hipMemsetAsync(pooled,  0, (size_t)T*HID*4, stream);

  k_degree<<<(E+255)/256, 256, 0, stream>>>(src, dst, cnt_out, cnt_in, E);
  k_norms <<<(N+255)/256, 256, 0, stream>>>(cnt_out, cnt_in, norm_o, norm_i, N);
  k_scan  <<<1, 1024, 0, stream>>>(cnt_in, row_ptr, cursor, N);
  k_fill  <<<(E+255)/256, 256, 0, stream>>>(src, dst, cursor, es, E);

  k_fnT      <<<(N+63)/64, 256, 0, stream>>>(features, norm_o, fnT, N);
  k_gconv1_nm<<<N/4, 256, 0, stream>>>(fnT, row_ptr, es, norm_i, norm_o, W1, b1, h1s, N);
  k_gconv2_nm<<<N/4, 256, 0, stream>>>(h1s, row_ptr, es, norm_i, x2, N);

  k_w2frag<<<16, 256, 0, stream>>>(W2, W2F);

  const int NT = (N + 15) / 16;           // 625 16-node tiles
  const int GX = (NT + 3) / 4;            // 4 waves (tiles) per block
  k_linear_mfma<0><<<dim3(GX, T), 256, 0, stream>>>(x2, W2F, b2, gate_w, gate_b, gates, mz, pooled, N);
  k_softmax<<<T, 256, 0, stream>>>(gates, mz, N);
  k_linear_mfma<1><<<dim3(GX, T), 256, 0, stream>>>(x2, W2F, b2, gate_w, gate_b, gates, mz, pooled, N);

  k_transpose<<<(3*HID*HID+255)/256, 256, 0, stream>>>(W_ih, WT_ih, 3*HID, HID);
  k_transpose<<<(3*HID*HID+255)/256, 256, 0, stream>>>(W_hh, WT_hh, 3*HID, HID);
  k_gi <<<T, 3*HID, 0, stream>>>(pooled, WT_ih, b_ih, gi_all);
  k_gru<<<1, 3*HID, 0, stream>>>(gi_all, WT_hh, b_hh, d1_w, d1_b, d2_w, d2_b, out);
}

// Round 4
// 278.597 us; speedup vs baseline: 3.2686x; 1.4073x over previous
//
#include <hip/hip_runtime.h>
#include <stdint.h>

#define T_FRAMES 32
#define NNODES 10000
#define NEDGES 160000
#define HID 128

typedef short v8s __attribute__((ext_vector_type(8)));
typedef float v4f __attribute__((ext_vector_type(4)));

static __device__ __forceinline__ ushort f2bf(float f){
  uint32_t u = __float_as_uint(f);
  u += 0x7FFFu + ((u >> 16) & 1u);
  return (ushort)(u >> 16);
}
static __device__ __forceinline__ float bf_lo(uint32_t u){
  return __uint_as_float(u << 16);
}
static __device__ __forceinline__ float bf_hi(uint32_t u){
  return __uint_as_float(u & 0xffff0000u);
}
static __device__ __forceinline__ float silu_f(float x){
  return x / (1.0f + expf(-x));
}
static __device__ __forceinline__ float sigm_f(float x){
  return 1.0f / (1.0f + expf(-x));
}

// ---------------- degree / norms / CSR build ----------------

__global__ void k_degree(const int* __restrict__ src, const int* __restrict__ dst,
                         int* cnt_out, int* cnt_in, int E){
  int e = blockIdx.x*blockDim.x + threadIdx.x;
  if (e < E){
    atomicAdd(&cnt_out[src[e]], 1);
    atomicAdd(&cnt_in[dst[e]], 1);
  }
}

__global__ void k_norms(const int* __restrict__ cnt_out, const int* __restrict__ cnt_in,
                        float* norm_out, float* norm_in, int N){
  int n = blockIdx.x*blockDim.x + threadIdx.x;
  if (n < N){
    norm_out[n] = rsqrtf((float)max(cnt_out[n], 1));
    norm_in[n]  = rsqrtf((float)max(cnt_in[n], 1));
  }
}

__global__ void __launch_bounds__(1024) k_scan(const int* __restrict__ cnt_in,
                                               int* row_ptr, int* cursor, int N){
  __shared__ int sm[1024];
  __shared__ int carry_s;
  if (threadIdx.x == 0) carry_s = 0;
  __syncthreads();
  for (int base = 0; base < N; base += 1024){
    int i = base + threadIdx.x;
    int v = (i < N) ? cnt_in[i] : 0;
    sm[threadIdx.x] = v;
    __syncthreads();
    for (int off = 1; off < 1024; off <<= 1){
      int tv = (threadIdx.x >= off) ? sm[threadIdx.x - off] : 0;
      __syncthreads();
      sm[threadIdx.x] += tv;
      __syncthreads();
    }
    int excl = sm[threadIdx.x] - v;
    if (i < N){ row_ptr[i] = carry_s + excl; cursor[i] = carry_s + excl; }
    __syncthreads();
    if (threadIdx.x == 0) carry_s += sm[1023];
    __syncthreads();
  }
  if (threadIdx.x == 0) row_ptr[N] = carry_s;
}

__global__ void k_fill(const int* __restrict__ src, const int* __restrict__ dst,
                       int* cursor, int* es, int E){
  int e = blockIdx.x*blockDim.x + threadIdx.x;
  if (e < E){
    int p = atomicAdd(&cursor[dst[e]], 1);
    es[p] = src[e];
  }
}

// ---------------- transpose features -> node-major, pre-scaled by norm_out ----------------
// fnT[n][t] = features[t][n] * norm_out[n]

__global__ void __launch_bounds__(256) k_fnT(const float* __restrict__ feat,
                                             const float* __restrict__ norm_o,
                                             float* __restrict__ fnT, int N){
  __shared__ float sm[32][65];
  int n0 = blockIdx.x*64;
  int tid = threadIdx.x;
  for (int idx = tid; idx < 2048; idx += 256){
    int t = idx >> 6, i = idx & 63;
    int n = n0 + i;
    sm[t][i] = (n < N) ? feat[(size_t)t*N + n] : 0.f;
  }
  __syncthreads();
  for (int idx = tid; idx < 2048; idx += 256){
    int i = idx >> 5, t = idx & 31;
    int n = n0 + i;
    if (n < N) fnT[(size_t)n*32 + t] = sm[t][i] * norm_o[n];
  }
}

// ---------------- gconv1 (node-major): one wave per node ----------------
// x1[t] = norm_in[n] * sum_e fnT[es[e]][t]
// h1s[n][t][j] = silu(x1[t]*W1[j]+b1[j]) * norm_out[n]   (bf16, row = 2KB)

__global__ void __launch_bounds__(256) k_gconv1_nm(
    const float* __restrict__ fnT, const int* __restrict__ row_ptr,
    const int* __restrict__ es, const float* __restrict__ norm_in,
    const float* __restrict__ norm_out,
    const float* __restrict__ W1, const float* __restrict__ b1,
    ushort* __restrict__ h1s, int N){
  __shared__ float w1s[32], b1s[32];
  int tid = threadIdx.x;
  if (tid < 32){ w1s[tid] = W1[tid]; b1s[tid] = b1[tid]; }
  __syncthreads();
  int n = blockIdx.x*4 + (tid >> 6);          // N % 4 == 0
  int lane = tid & 63;
  int ep = lane >> 5, t = lane & 31;
  int s = row_ptr[n], d = row_ptr[n+1];
  float acc = 0.f;
  for (int e = s + ep; e < d; e += 2)
    acc += fnT[(size_t)es[e]*32 + t];
  acc += __shfl_xor(acc, 32);
  float x1 = acc * norm_in[n];                // valid at lanes t and t+32
  float x1p = __shfl(x1, lane >> 1);          // lane l gets x1[t = l>>1]
  float no = norm_out[n];
  int j0 = (lane & 1) * 16;
  uint w[8];
  #pragma unroll
  for (int q = 0; q < 8; ++q){
    float h0 = silu_f(fmaf(x1p, w1s[j0+2*q],   b1s[j0+2*q]))   * no;
    float h1 = silu_f(fmaf(x1p, w1s[j0+2*q+1], b1s[j0+2*q+1])) * no;
    w[q] = (uint)f2bf(h0) | ((uint)f2bf(h1) << 16);
  }
  uint4* dp = (uint4*)(h1s + (size_t)n*1024 + lane*16);
  dp[0] = make_uint4(w[0], w[1], w[2], w[3]);
  dp[1] = make_uint4(w[4], w[5], w[6], w[7]);
}

// ---------------- gconv2 (node-major): one wave per node ----------------
// x2[n][t][j] = norm_in[n] * sum_e h1s[es[e]][t][j]  — each edge = 2KB coalesced read

__global__ void __launch_bounds__(256) k_gconv2_nm(
    const ushort* __restrict__ h1s, const int* __restrict__ row_ptr,
    const int* __restrict__ es, const float* __restrict__ norm_in,
    ushort* __restrict__ x2, int N){
  int tid = threadIdx.x;
  int n = blockIdx.x*4 + (tid >> 6);
  int lane = tid & 63;
  int s = row_ptr[n], d = row_ptr[n+1];
  float acc[16];
  #pragma unroll
  for (int i = 0; i < 16; ++i) acc[i] = 0.f;

  #define ACC_U4(v, base) do { \
    acc[(base)+0] += bf_lo((v).x); acc[(base)+1] += bf_hi((v).x); \
    acc[(base)+2] += bf_lo((v).y); acc[(base)+3] += bf_hi((v).y); \
    acc[(base)+4] += bf_lo((v).z); acc[(base)+5] += bf_hi((v).z); \
    acc[(base)+6] += bf_lo((v).w); acc[(base)+7] += bf_hi((v).w); \
  } while(0)

  int e = s;
  for (; e + 1 < d; e += 2){
    const uint4* p0 = (const uint4*)(h1s + (size_t)es[e]  *1024) + lane*2;
    const uint4* p1 = (const uint4*)(h1s + (size_t)es[e+1]*1024) + lane*2;
    uint4 a0 = p0[0], a1 = p0[1];
    uint4 c0 = p1[0], c1 = p1[1];
    ACC_U4(a0, 0); ACC_U4(a1, 8);
    ACC_U4(c0, 0); ACC_U4(c1, 8);
  }
  if (e < d){
    const uint4* p0 = (const uint4*)(h1s + (size_t)es[e]*1024) + lane*2;
    uint4 a0 = p0[0], a1 = p0[1];
    ACC_U4(a0, 0); ACC_U4(a1, 8);
  }
  #undef ACC_U4

  float ni = norm_in[n];
  uint w[8];
  #pragma unroll
  for (int q = 0; q < 8; ++q)
    w[q] = (uint)f2bf(acc[2*q]*ni) | ((uint)f2bf(acc[2*q+1]*ni) << 16);
  uint4* dp = (uint4*)(x2 + (size_t)n*1024 + lane*16);
  dp[0] = make_uint4(w[0], w[1], w[2], w[3]);
  dp[1] = make_uint4(w[4], w[5], w[6], w[7]);
}

// ---------------- W2 -> bf16 MFMA B-fragments ----------------
// W2F[i][l][j] (i=frag 0..7, l=lane 0..63, j=0..7): W2bf[k=(l>>4)*8+j][i*16 + (l&15)]

__global__ void k_w2frag(const float* __restrict__ W2, ushort* __restrict__ W2F){
  int tid = blockIdx.x*blockDim.x + threadIdx.x;  // 0..4095
  int j = tid & 7, l = (tid >> 3) & 63, i = tid >> 9;
  int g = l >> 4, n = l & 15;
  W2F[tid] = f2bf(W2[(g*8 + j)*128 + i*16 + n]);
}

// ---------------- linear 32->128 + silu via MFMA (x2 node-major) ----------------
// PHASE 0: gates[t][n] = silu(x2@W2+b2) . gate_w + gate_b
// PHASE 1: pooled[t][:] += softmax-weight[n] * silu(x2@W2+b2)

template<int PHASE>
__global__ void __launch_bounds__(256) k_linear_mfma(
    const ushort* __restrict__ x2, const ushort* __restrict__ W2F,
    const float* __restrict__ b2, const float* __restrict__ gate_w,
    const float* __restrict__ gate_b,
    float* __restrict__ gates, const float* __restrict__ mz,
    float* __restrict__ pooled, int N){
  __shared__ float pool_s[128];
  int t = blockIdx.y;
  int tid = threadIdx.x;
  int wave = tid >> 6, lane = tid & 63;
  int g = lane >> 4, n = lane & 15;
  if (PHASE == 1){
    if (tid < 128) pool_s[tid] = 0.f;
    __syncthreads();
  }
  int tile = blockIdx.x*4 + wave;          // 16-node tile; N = 625*16
  bool active = (tile*16 < N);

  const v8s* W2Fv = (const v8s*)W2F;
  v8s bfrag[8];
  #pragma unroll
  for (int i = 0; i < 8; ++i) bfrag[i] = W2Fv[i*64 + lane];
  v4f acc[8];
  #pragma unroll
  for (int i = 0; i < 8; ++i){
    float bv = b2[i*16 + n];
    acc[i] = (v4f){bv, bv, bv, bv};
  }
  if (active){
    int nb = tile*16;
    // x2 element index: node*1024 + t*32 + j ; lane reads node nb+(lane&15), k-chunk g*8..
    const v8s* ap = (const v8s*)(x2 + (size_t)(nb + (lane & 15))*1024 + t*32);
    v8s a = ap[g];
    #pragma unroll
    for (int i = 0; i < 8; ++i)
      acc[i] = __builtin_amdgcn_mfma_f32_16x16x32_bf16(a, bfrag[i], acc[i], 0, 0, 0);
  }
  // C/D layout: value (i,r) = h[node nb + g*4 + r][col i*16 + n]
  if (PHASE == 0){
    if (active){
      float gw8[8];
      #pragma unroll
      for (int i = 0; i < 8; ++i) gw8[i] = gate_w[i*16 + n];
      float gp[4] = {0.f, 0.f, 0.f, 0.f};
      #pragma unroll
      for (int i = 0; i < 8; ++i){
        #pragma unroll
        for (int r = 0; r < 4; ++r) gp[r] += silu_f(acc[i][r]) * gw8[i];
      }
      #pragma unroll
      for (int m = 1; m < 16; m <<= 1){
        #pragma unroll
        for (int r = 0; r < 4; ++r) gp[r] += __shfl_xor(gp[r], m);
      }
      if (n == 0){
        int nb = tile*16;
        float gb = gate_b[0];
        #pragma unroll
        for (int r = 0; r < 4; ++r) gates[(size_t)t*N + nb + g*4 + r] = gp[r] + gb;
      }
    }
  } else {
    if (active){
      int nb = tile*16;
      float m0 = mz[2*t], invZ = mz[2*t+1];
      float wn[4];
      #pragma unroll
      for (int r = 0; r < 4; ++r)
        wn[r] = expf(gates[(size_t)t*N + nb + g*4 + r] - m0) * invZ;
      float cs[8];
      #pragma unroll
      for (int i = 0; i < 8; ++i){
        float c = 0.f;
        #pragma unroll
        for (int r = 0; r < 4; ++r) c += silu_f(acc[i][r]) * wn[r];
        c += __shfl_xor(c, 16);
        c += __shfl_xor(c, 32);
        cs[i] = c;
      }
      if (lane < 16){
        #pragma unroll
        for (int i = 0; i < 8; ++i) atomicAdd(&pool_s[i*16 + lane], cs[i]);
      }
    }
    __syncthreads();
    if (tid < 128) atomicAdd(&pooled[(size_t)t*HID + tid], pool_s[tid]);
  }
}

// ---------------- softmax stats per frame ----------------

__global__ void k_softmax(const float* __restrict__ gates, float* mz, int N){
  __shared__ float red[256];
  int t = blockIdx.x, tid = threadIdx.x;
  const float* g = gates + (size_t)t*N;
  float mx = -1e30f;
  for (int i = tid; i < N; i += 256) mx = fmaxf(mx, g[i]);
  red[tid] = mx; __syncthreads();
  for (int off = 128; off > 0; off >>= 1){
    if (tid < off) red[tid] = fmaxf(red[tid], red[tid+off]);
    __syncthreads();
  }
  float m = red[0]; __syncthreads();
  float se = 0.f;
  for (int i = tid; i < N; i += 256) se += expf(g[i] - m);
  red[tid] = se; __syncthreads();
  for (int off = 128; off > 0; off >>= 1){
    if (tid < off) red[tid] += red[tid+off];
    __syncthreads();
  }
  if (tid == 0){ mz[2*t] = m; mz[2*t+1] = 1.0f/red[0]; }
}

// ---------------- GRU + head ----------------

__global__ void k_transpose(const float* __restrict__ W, float* __restrict__ WT,
                            int rows /*3H*/, int cols /*H*/){
  int idx = blockIdx.x*blockDim.x + threadIdx.x;  // WT[j*rows + o] = W[o*cols + j]
  if (idx < rows*cols){
    int j = idx / rows;
    int o = idx % rows;
    WT[idx] = W[o*cols + j];
  }
}

__global__ void k_gi(const float* __restrict__ pooled, const float* __restrict__ WT_ih,
                     const float* __restrict__ b_ih, float* __restrict__ gi_all){
  __shared__ float ps[HID];
  int t = blockIdx.x, tid = threadIdx.x;   // 384 threads
  if (tid < HID) ps[tid] = pooled[(size_t)t*HID + tid];
  __syncthreads();
  float acc = b_ih[tid];
  #pragma unroll 4
  for (int j = 0; j < HID; ++j) acc = fmaf(ps[j], WT_ih[j*384 + tid], acc);
  gi_all[t*384 + tid] = acc;
}

// weights held in 128 VGPRs per thread; gi staged in LDS; h broadcast via LDS.
__global__ void __launch_bounds__(384) k_gru(
    const float* __restrict__ gi_all, const float* __restrict__ WT_hh,
    const float* __restrict__ b_hh,
    const float* __restrict__ d1_w, const float* __restrict__ d1_b,
    const float* __restrict__ d2_w, const float* __restrict__ d2_b,
    float* __restrict__ out){
  __shared__ float gi_s[T_FRAMES*3*HID];   // 48 KB
  __shared__ float h_s[HID];
  __shared__ float gh_s[3*HID];
  __shared__ float o1[16];
  int tid = threadIdx.x;  // 384

  // stage gi (32 coalesced rounds)
  for (int i = tid; i < T_FRAMES*3*HID; i += 384) gi_s[i] = gi_all[i];

  // per-thread weight column in registers
  float w[HID];
  #pragma unroll
  for (int j = 0; j < HID; ++j) w[j] = WT_hh[j*384 + tid];
  float bh = b_hh[tid];

  if (tid < HID) h_s[tid] = 0.f;
  __syncthreads();

  for (int t = 0; t < T_FRAMES; ++t){
    float acc = bh;
    const float4* h4 = (const float4*)h_s;
    #pragma unroll
    for (int q = 0; q < HID/4; ++q){
      float4 hv = h4[q];
      acc = fmaf(w[4*q+0], hv.x, acc);
      acc = fmaf(w[4*q+1], hv.y, acc);
      acc = fmaf(w[4*q+2], hv.z, acc);
      acc = fmaf(w[4*q+3], hv.w, acc);
    }
    gh_s[tid] = acc;
    __syncthreads();
    if (tid < HID){
      const float* gi = gi_s + t*384;
      float r  = sigm_f(gi[tid]       + gh_s[tid]);
      float z  = sigm_f(gi[HID+tid]   + gh_s[HID+tid]);
      float nn = tanhf(gi[2*HID+tid] + r*gh_s[2*HID+tid]);
      h_s[tid] = (1.f - z)*nn + z*h_s[tid];
    }
    __syncthreads();
  }
  if (tid < 16){
    float acc = d1_b[tid];
    #pragma unroll 4
    for (int j = 0; j < HID; ++j) acc = fmaf(h_s[j], d1_w[j*16 + tid], acc);
    o1[tid] = silu_f(acc);
  }
  __syncthreads();
  if (tid < 4){
    float acc = d2_b[tid];
    #pragma unroll
    for (int j = 0; j < 16; ++j) acc = fmaf(o1[j], d2_w[j*4 + tid], acc);
    out[tid] = sigm_f(silu_f(acc));
  }
}

// ---------------- launch ----------------

extern "C" void kernel_launch(void* const* d_in, const int* in_sizes, int n_in,
                              void* d_out, int out_size, void* d_ws, size_t ws_size,
                              hipStream_t stream){
  const float* features = (const float*)d_in[0];
  const int*   src      = (const int*)  d_in[1];
  const int*   dst      = (const int*)  d_in[2];
  const float* W1       = (const float*)d_in[3];
  const float* b1       = (const float*)d_in[4];
  const float* W2       = (const float*)d_in[5];
  const float* b2       = (const float*)d_in[6];
  const float* gate_w   = (const float*)d_in[7];
  const float* gate_b   = (const float*)d_in[8];
  const float* W_ih     = (const float*)d_in[9];
  const float* W_hh     = (const float*)d_in[10];
  const float* b_ih     = (const float*)d_in[11];
  const float* b_hh     = (const float*)d_in[12];
  const float* d1_w     = (const float*)d_in[13];
  const float* d1_b     = (const float*)d_in[14];
  const float* d2_w     = (const float*)d_in[15];
  const float* d2_b     = (const float*)d_in[16];
  float* out = (float*)d_out;

  const int N = NNODES, E = NEDGES, T = T_FRAMES;

  char* base = (char*)d_ws;
  size_t off = 0;
  auto alloc = [&](size_t bytes)->void*{
    void* p = base + off;
    off = (off + bytes + 255) & ~(size_t)255;
    return p;
  };
  int*    cnt_out = (int*)   alloc((size_t)N*4);
  int*    cnt_in  = (int*)   alloc((size_t)N*4);
  int*    row_ptr = (int*)   alloc((size_t)(N+1)*4);
  int*    cursor  = (int*)   alloc((size_t)N*4);
  float*  norm_o  = (float*) alloc((size_t)N*4);
  float*  norm_i  = (float*) alloc((size_t)N*4);
  int*    es      = (int*)   alloc((size_t)E*4);
  float*  fnT     = (float*) alloc((size_t)N*T*4);
  ushort* h1s     = (ushort*)alloc((size_t)N*T*32*2);
  ushort* x2      = (ushort*)alloc((size_t)N*T*32*2);
  float*  gates   = (float*) alloc((size_t)T*N*4);
  float*  mz      = (float*) alloc((size_t)T*2*4);
  float*  pooled  = (float*) alloc((size_t)T*HID*4);
  float*  gi_all  = (float*) alloc((size_t)T*3*HID*4);
  float*  WT_ih   = (float*) alloc((size_t)3*HID*HID*4);
  float*  WT_hh   = (float*) alloc((size_t)3*HID*HID*4);
  ushort* W2F     = (ushort*)alloc((size_t)8*64*8*2);
  (void)ws_size; (void)in_sizes; (void)n_in; (void)out_size;

  hipMemsetAsync(cnt_out, 0, (size_t)N*4, stream);
  hipMemsetAsync(cnt_in,  0, (size_t)N*4, stream);
  hipMemsetAsync(pooled,  0, (size_t)T*HID*4, stream);

  k_degree<<<(E+255)/256, 256, 0, stream>>>(src, dst, cnt_out, cnt_in, E);
  k_norms <<<(N+255)/256, 256, 0, stream>>>(cnt_out, cnt_in, norm_o, norm_i, N);
  k_scan  <<<1, 1024, 0, stream>>>(cnt_in, row_ptr, cursor, N);
  k_fill  <<<(E+255)/256, 256, 0, stream>>>(src, dst, cursor, es, E);

  k_fnT      <<<(N+63)/64, 256, 0, stream>>>(features, norm_o, fnT, N);
  k_gconv1_nm<<<N/4, 256, 0, stream>>>(fnT, row_ptr, es, norm_i, norm_o, W1, b1, h1s, N);
  k_gconv2_nm<<<N/4, 256, 0, stream>>>(h1s, row_ptr, es, norm_i, x2, N);

  k_w2frag<<<16, 256, 0, stream>>>(W2, W2F);

  const int NT = (N + 15) / 16;           // 625 16-node tiles
  const int GX = (NT + 3) / 4;            // 4 waves (tiles) per block
  k_linear_mfma<0><<<dim3(GX, T), 256, 0, stream>>>(x2, W2F, b2, gate_w, gate_b, gates, mz, pooled, N);
  k_softmax<<<T, 256, 0, stream>>>(gates, mz, N);
  k_linear_mfma<1><<<dim3(GX, T), 256, 0, stream>>>(x2, W2F, b2, gate_w, gate_b, gates, mz, pooled, N);

  k_transpose<<<(3*HID*HID+255)/256, 256, 0, stream>>>(W_ih, WT_ih, 3*HID, HID);
  k_transpose<<<(3*HID*HID+255)/256, 256, 0, stream>>>(W_hh, WT_hh, 3*HID, HID);
  k_gi <<<T, 3*HID, 0, stream>>>(pooled, WT_ih, b_ih, gi_all);
  k_gru<<<1, 3*HID, 0, stream>>>(gi_all, WT_hh, b_hh, d1_w, d1_b, d2_w, d2_b, out);
}